// Round 12
// baseline (153.683 us; speedup 1.0000x reference)
//
#include <hip/hip_runtime.h>
#include <hip/hip_bf16.h>

#define DDIM 256
#define NROWS 8192

typedef __attribute__((ext_vector_type(4))) int int4v;
typedef __attribute__((ext_vector_type(8))) int int8v;
typedef __attribute__((ext_vector_type(16))) float f32x16;

// async global->LDS, 16B per lane. LDS dest is wave-uniform base + lane*16.
__device__ __forceinline__ void async16(const void* g, void* l) {
    __builtin_amdgcn_global_load_lds(
        (const __attribute__((address_space(1))) unsigned int*)g,
        (__attribute__((address_space(3))) unsigned int*)l,
        16, 0, 0);
}

// raw v_exp_f32: returns 2^x (one transcendental)
__device__ __forceinline__ float fexp2(float x) {
    float r; asm("v_exp_f32 %0, %1" : "=v"(r) : "v"(x)); return r;
}

// Kernel 1: L2-normalize rows of U and P to FP8 e4m3 (OCP), compute pos_sim
// in fp32 (exact), zero rowsum / out / ticket counter. One wave per row.
__global__ __launch_bounds__(256) void normalize_kernel(
    const float* __restrict__ U, const float* __restrict__ P,
    unsigned char* __restrict__ Un, unsigned char* __restrict__ Pn,
    float* __restrict__ possim, float* __restrict__ rowsum,
    float* __restrict__ out, int* __restrict__ counter)
{
    if (blockIdx.x == 0 && threadIdx.x == 0) { out[0] = 0.0f; counter[0] = 0; }
    const int lane = threadIdx.x & 63;
    const int row  = blockIdx.x * 4 + (threadIdx.x >> 6);
    const size_t fbase = (size_t)row * DDIM + lane * 4;
    const float4 u4 = *(const float4*)(U + fbase);
    const float4 p4 = *(const float4*)(P + fbase);
    float su = u4.x*u4.x + u4.y*u4.y + u4.z*u4.z + u4.w*u4.w;
    float sp = p4.x*p4.x + p4.y*p4.y + p4.z*p4.z + p4.w*p4.w;
    float up = u4.x*p4.x + u4.y*p4.y + u4.z*p4.z + u4.w*p4.w;
    #pragma unroll
    for (int d = 1; d < 64; d <<= 1) {
        su += __shfl_xor(su, d);
        sp += __shfl_xor(sp, d);
        up += __shfl_xor(up, d);
    }
    const float iu = rsqrtf(fmaxf(su, 1e-24f));
    const float ip = rsqrtf(fmaxf(sp, 1e-24f));
    if (lane == 0) {
        possim[row] = up * iu * ip;
        rowsum[row] = 0.0f;
    }
    unsigned pu = (unsigned)__builtin_amdgcn_cvt_pk_fp8_f32(u4.x*iu, u4.y*iu, 0, false);
    pu = (unsigned)__builtin_amdgcn_cvt_pk_fp8_f32(u4.z*iu, u4.w*iu, (int)pu, true);
    unsigned pp = (unsigned)__builtin_amdgcn_cvt_pk_fp8_f32(p4.x*ip, p4.y*ip, 0, false);
    pp = (unsigned)__builtin_amdgcn_cvt_pk_fp8_f32(p4.z*ip, p4.w*ip, (int)pp, true);
    *(unsigned*)(Un + (size_t)row * DDIM + lane * 4) = pu;
    *(unsigned*)(Pn + (size_t)row * DDIM + lane * 4) = pp;
}

// Kernel 2: persistent-A FP8 GEMM (mfma_scale_f32_32x32x64_f8f6f4, unit
// E8M0 scales = plain fp8 at 2x bf16 rate) + exp-rowsum + fused finalize.
// R12: R11's kernel (proven 67.2 us, absmax 0.0) with 2 blocks/CU:
//   512 blocks x 512 thr (8 waves). Block = 256 rows x 512 cols, 8 slots
//   of 64 cols. Same 64 KB quad-buffered LDS, same counted-vmcnt ladder,
//   same fragment/swizzle math. VGPR 60 + 64 KB LDS -> genuinely 2
//   blocks/CU = 16 waves/CU: co-resident block fills the ~50 us of
//   per-block dead time (all pipes <25% busy at 1 block/CU). R4's failed
//   co-residency test had spill (WRITE 11 MB) + 2x LDS traffic (bf16);
//   both confounds are gone at fp8. Slot count per block also halves
//   (8 barriers + 8 vm-waits instead of 16).
// Fragment layouts (32x32x64 f8f6f4):
//   A: row = lane&31, k = (lane>>5)*32 + i ;  B symmetric (col = lane&31)
//   C/D: col = lane&31, row = (reg&3) + 8*(reg>>2) + 4*(lane>>5)
// LDS tile 64 rows x 256 B; granule-16 XOR swizzle g^(row&15), involution
// applied on async16 SOURCE and ds_read addr (rule #21).
__global__ __launch_bounds__(512, 4) void sim_exp_rowsum(
    const unsigned char* __restrict__ Un,
    const unsigned char* __restrict__ Pn,
    float* __restrict__ rowsum,
    const float* __restrict__ possim,
    int* __restrict__ counter,
    float* __restrict__ out)
{
    __shared__ __align__(16) unsigned char lds[65536];   // 4 x 16 KB fp8 B bufs
    __shared__ float ws8[8];
    __shared__ int ticket_s;

    const int tid  = threadIdx.x;
    const int lane = tid & 63;
    const int wv   = tid >> 6;          // 0..7, each wave owns 32 A-rows
    const int m32  = lane & 31;
    const int hi   = lane >> 5;

    const int stripe = blockIdx.x >> 4;   // 0..31  (256-row stripes)
    const int cg     = blockIdx.x & 15;   // 0..15  (512-col groups; &7 = XCD)

    // ---- A-frags straight from global fp8 (one-time, L2/L3-hot) ----
    const unsigned char* Arow = Un
        + (size_t)(stripe * 256 + wv * 32 + m32) * DDIM + hi * 32;
    union A8 { int8v v; int4v h[2]; };
    A8 afr[4];
    #pragma unroll
    for (int kc = 0; kc < 4; ++kc) {
        afr[kc].h[0] = *(const int4v*)(Arow + kc * 64);
        afr[kc].h[1] = *(const int4v*)(Arow + kc * 64 + 16);
    }

    // ---- B LDS addressing (swizzle pre-folded) ----
    // addr = m32*256 + ((hi*2+h)^xlo)*16 + (kc*64 ^ xh16) + n*8192
    const int x = m32 & 15, xlo = x & 3;
    const unsigned xh16 = (unsigned)((x & 12) * 16);
    const unsigned bA = (unsigned)(m32 * 256 + (((hi * 2 + 0) ^ xlo) * 16));
    const unsigned bB = (unsigned)(m32 * 256 + (((hi * 2 + 1) ^ xlo) * 16));
    unsigned kterm[4];
    #pragma unroll
    for (int kc = 0; kc < 4; ++kc)
        kterm[kc] = (unsigned)(kc * 64) ^ xh16;

    // ---- staging offsets: wave stages 8 rows (2 KB) per tile, 2 async16 ----
    unsigned soff0, soff1;
    {
        const int r0 = wv * 8 + 0 * 4 + (lane >> 4);
        const int r1 = wv * 8 + 1 * 4 + (lane >> 4);
        const int gp = lane & 15;
        soff0 = (unsigned)(r0 * 256 + ((gp ^ (r0 & 15)) * 16));
        soff1 = (unsigned)(r1 * 256 + ((gp ^ (r1 & 15)) * 16));
    }

    const unsigned char* Bglob = Pn + (size_t)(cg * 512) * DDIM;

#define STG(T, BUF)                                                          \
    do {                                                                     \
        async16(Bglob + (size_t)(T) * 16384 + soff0,                         \
                lds + (BUF) * 16384 + wv * 2048);                            \
        async16(Bglob + (size_t)(T) * 16384 + soff1,                         \
                lds + (BUF) * 16384 + wv * 2048 + 1024);                     \
    } while (0)

    float rowpart[16];
    #pragma unroll
    for (int g = 0; g < 16; ++g) rowpart[g] = 0.0f;

    // ---- Prologue: stage tiles 0..2, full drain (also covers A-loads) ----
    STG(0, 0); STG(1, 1); STG(2, 2);
    asm volatile("s_waitcnt vmcnt(0)" ::: "memory");
    __builtin_amdgcn_s_barrier();

    // ---- Main loop: 8 col-slots of 64 fp8 cols ----
    // slot-top accounting: outstanding before wait = tiles {i,i+1,i+2}
    // (6 loads max); vmcnt(4) drains tile i. Slots 6/7: 2/0 remain.
    for (int i = 0; i < 8; ++i) {
        if (i > 0) {
            if (i <= 5)       asm volatile("s_waitcnt vmcnt(4)" ::: "memory");
            else if (i == 6)  asm volatile("s_waitcnt vmcnt(2)" ::: "memory");
            else              asm volatile("s_waitcnt vmcnt(0)" ::: "memory");
            __builtin_amdgcn_s_barrier();   // frees buf (i+3)&3
        }
        if (i + 3 < 8) STG(i + 3, (i + 3) & 3);

        const unsigned char* Bp = lds + (i & 3) * 16384;
        f32x16 acc0, acc1;
        #pragma unroll
        for (int g = 0; g < 16; ++g) { acc0[g] = 0.0f; acc1[g] = 0.0f; }

        #pragma unroll
        for (int kc = 0; kc < 4; ++kc) {
            A8 b0, b1;
            b0.h[0] = *(const int4v*)(Bp + bA + kterm[kc]);
            b0.h[1] = *(const int4v*)(Bp + bB + kterm[kc]);
            b1.h[0] = *(const int4v*)(Bp + bA + kterm[kc] + 8192);
            b1.h[1] = *(const int4v*)(Bp + bB + kterm[kc] + 8192);
            __builtin_amdgcn_s_setprio(1);
            acc0 = __builtin_amdgcn_mfma_scale_f32_32x32x64_f8f6f4(
                afr[kc].v, b0.v, acc0, 0, 0,
                0, 0x7F7F7F7F, 0, 0x7F7F7F7F);   // fp8/fp8, unit scales
            acc1 = __builtin_amdgcn_mfma_scale_f32_32x32x64_f8f6f4(
                afr[kc].v, b1.v, acc1, 0, 0,
                0, 0x7F7F7F7F, 0, 0x7F7F7F7F);
            __builtin_amdgcn_s_setprio(0);
        }

        // exp(5*sim) = 2^(sim*5*log2 e)
        #pragma unroll
        for (int g = 0; g < 16; ++g)
            rowpart[g] += fexp2(acc0[g] * 7.2134752044448169f)
                        + fexp2(acc1[g] * 7.2134752044448169f);
    }
#undef STG

    // ---- Epilogue: reduce 32 column-lanes, one atomic per row-slot ----
    // C/D: col = lane&31, row = (g&3) + 8*(g>>2) + 4*hi.
    #pragma unroll
    for (int g = 0; g < 16; ++g) {
        float s = rowpart[g];
        s += __shfl_xor(s, 1);
        s += __shfl_xor(s, 2);
        s += __shfl_xor(s, 4);
        s += __shfl_xor(s, 8);
        s += __shfl_xor(s, 16);
        if (m32 == 0) {
            const int grow = stripe * 256 + wv * 32
                           + (g & 3) + 8 * (g >> 2) + 4 * hi;
            atomicAdd(&rowsum[grow], s);
        }
    }

    // ---- Fused finalize: last block computes the loss ----
    __threadfence();
    __syncthreads();   // this block's atomics are visible
    if (tid == 0)
        ticket_s = __hip_atomic_fetch_add(counter, 1, __ATOMIC_ACQ_REL,
                                          __HIP_MEMORY_SCOPE_AGENT);
    __syncthreads();
    if (ticket_s == 511) {
        float part = 0.0f;
        for (int i = tid; i < NROWS; i += 512) {
            const float rs = __hip_atomic_load(&rowsum[i], __ATOMIC_RELAXED,
                                               __HIP_MEMORY_SCOPE_AGENT);
            part += __logf(rs) - 5.0f * possim[i];
        }
        #pragma unroll
        for (int d = 1; d < 64; d <<= 1) part += __shfl_xor(part, d);
        if ((tid & 63) == 0) ws8[wv] = part;
        __syncthreads();
        if (tid == 0) {
            float tot = 0.0f;
            #pragma unroll
            for (int w = 0; w < 8; ++w) tot += ws8[w];
            out[0] = tot * (1.0f / (float)NROWS);
        }
    }
}

extern "C" void kernel_launch(void* const* d_in, const int* in_sizes, int n_in,
                              void* d_out, int out_size, void* d_ws, size_t ws_size,
                              hipStream_t stream) {
    const float* U = (const float*)d_in[0];
    const float* P = (const float*)d_in[1];
    float* out = (float*)d_out;
    char* ws = (char*)d_ws;
    // ws: Un fp8 (2 MB) | Pn fp8 (2 MB) | ... | rowsum f32 @8 MB | possim | counter
    unsigned char* Un = (unsigned char*)ws;
    unsigned char* Pn = (unsigned char*)(ws + 2097152);
    float* rowsum = (float*)(ws + 8388608);
    float* possim = (float*)(ws + 8388608 + 32768);
    int* counter  = (int*)(ws + 8388608 + 65536);

    normalize_kernel<<<NROWS / 4, 256, 0, stream>>>(U, P, Un, Pn, possim, rowsum,
                                                    out, counter);
    sim_exp_rowsum<<<512, 512, 0, stream>>>(Un, Pn, rowsum, possim, counter, out);
}

// Round 13
// 127.559 us; speedup vs baseline: 1.2048x; 1.2048x over previous
//
#include <hip/hip_runtime.h>
#include <hip/hip_bf16.h>

#define DDIM 256
#define NROWS 8192

typedef __attribute__((ext_vector_type(4))) int int4v;
typedef __attribute__((ext_vector_type(8))) int int8v;
typedef __attribute__((ext_vector_type(16))) float f32x16;

// async global->LDS, 16B per lane. LDS dest is wave-uniform base + lane*16.
__device__ __forceinline__ void async16(const void* g, void* l) {
    __builtin_amdgcn_global_load_lds(
        (const __attribute__((address_space(1))) unsigned int*)g,
        (__attribute__((address_space(3))) unsigned int*)l,
        16, 0, 0);
}

// raw v_exp_f32: returns 2^x (one transcendental)
__device__ __forceinline__ float fexp2(float x) {
    float r; asm("v_exp_f32 %0, %1" : "=v"(r) : "v"(x)); return r;
}

// Kernel 1: L2-normalize rows of U and P to FP8 e4m3 (OCP), compute pos_sim
// in fp32 (exact), zero rowsum / out / ticket counter. One wave per row.
__global__ __launch_bounds__(256) void normalize_kernel(
    const float* __restrict__ U, const float* __restrict__ P,
    unsigned char* __restrict__ Un, unsigned char* __restrict__ Pn,
    float* __restrict__ possim, float* __restrict__ rowsum,
    float* __restrict__ out, int* __restrict__ counter)
{
    if (blockIdx.x == 0 && threadIdx.x == 0) { out[0] = 0.0f; counter[0] = 0; }
    const int lane = threadIdx.x & 63;
    const int row  = blockIdx.x * 4 + (threadIdx.x >> 6);
    const size_t fbase = (size_t)row * DDIM + lane * 4;
    const float4 u4 = *(const float4*)(U + fbase);
    const float4 p4 = *(const float4*)(P + fbase);
    float su = u4.x*u4.x + u4.y*u4.y + u4.z*u4.z + u4.w*u4.w;
    float sp = p4.x*p4.x + p4.y*p4.y + p4.z*p4.z + p4.w*p4.w;
    float up = u4.x*p4.x + u4.y*p4.y + u4.z*p4.z + u4.w*p4.w;
    #pragma unroll
    for (int d = 1; d < 64; d <<= 1) {
        su += __shfl_xor(su, d);
        sp += __shfl_xor(sp, d);
        up += __shfl_xor(up, d);
    }
    const float iu = rsqrtf(fmaxf(su, 1e-24f));
    const float ip = rsqrtf(fmaxf(sp, 1e-24f));
    if (lane == 0) {
        possim[row] = up * iu * ip;
        rowsum[row] = 0.0f;
    }
    unsigned pu = (unsigned)__builtin_amdgcn_cvt_pk_fp8_f32(u4.x*iu, u4.y*iu, 0, false);
    pu = (unsigned)__builtin_amdgcn_cvt_pk_fp8_f32(u4.z*iu, u4.w*iu, (int)pu, true);
    unsigned pp = (unsigned)__builtin_amdgcn_cvt_pk_fp8_f32(p4.x*ip, p4.y*ip, 0, false);
    pp = (unsigned)__builtin_amdgcn_cvt_pk_fp8_f32(p4.z*ip, p4.w*ip, (int)pp, true);
    *(unsigned*)(Un + (size_t)row * DDIM + lane * 4) = pu;
    *(unsigned*)(Pn + (size_t)row * DDIM + lane * 4) = pp;
}

// Kernel 2: persistent-A FP8 GEMM (mfma_scale_f32_32x32x64_f8f6f4, unit
// E8M0 scales = plain fp8) + exp-rowsum + fused finalize.
// R13 = R11 (proven 67.2 us, absmax 0.0) with HALF THE SLOTS at DOUBLE
// WIDTH: 8 col-slots of 128 cols, quad-buffered 4 x 32 KB (128 KB LDS,
// 1 block/CU), depth-3 prefetch. The full round record fits
// sim ~= N_slots x (fixed ~5-7k cy) + work -- slot-count is the one
// untested axis (LDS only permits 128-col quad-buffering at fp8).
// Everything else (grid 256 x 512, fragment/swizzle math, counted-vmcnt
// ladder, epilogue) identical to R11.
// Fragment layouts (32x32x64 f8f6f4):
//   A: row = lane&31, k = (lane>>5)*32 + i ;  B symmetric (col = lane&31)
//   C/D: col = lane&31, row = (g&3) + 8*(g>>2) + 4*(lane>>5)
// LDS tile 128 rows x 256 B; granule-16 XOR swizzle g^(row&15), involution
// applied on async16 SOURCE and ds_read addr (rule #21).
__global__ __launch_bounds__(512, 2) void sim_exp_rowsum(
    const unsigned char* __restrict__ Un,
    const unsigned char* __restrict__ Pn,
    float* __restrict__ rowsum,
    const float* __restrict__ possim,
    int* __restrict__ counter,
    float* __restrict__ out)
{
    __shared__ __align__(16) unsigned char lds[131072];   // 4 x 32 KB fp8 B bufs
    __shared__ float ws8[8];
    __shared__ int ticket_s;

    const int tid  = threadIdx.x;
    const int lane = tid & 63;
    const int wv   = tid >> 6;          // 0..7, each wave owns 32 A-rows
    const int m32  = lane & 31;
    const int hi   = lane >> 5;

    const int stripe = blockIdx.x >> 3;   // 0..31  (256-row stripes)
    const int oct    = blockIdx.x & 7;    // 0..7   (1024-col groups == XCD)

    // ---- A-frags straight from global fp8 (one-time, L2/L3-hot) ----
    const unsigned char* Arow = Un
        + (size_t)(stripe * 256 + wv * 32 + m32) * DDIM + hi * 32;
    union A8 { int8v v; int4v h[2]; };
    A8 afr[4];
    #pragma unroll
    for (int kc = 0; kc < 4; ++kc) {
        afr[kc].h[0] = *(const int4v*)(Arow + kc * 64);
        afr[kc].h[1] = *(const int4v*)(Arow + kc * 64 + 16);
    }

    // ---- B LDS addressing (swizzle pre-folded) ----
    // addr = m32*256 + ((hi*2+h)^xlo)*16 + (kc*64 ^ xh16) + n*8192
    const int x = m32 & 15, xlo = x & 3;
    const unsigned xh16 = (unsigned)((x & 12) * 16);
    const unsigned bA = (unsigned)(m32 * 256 + (((hi * 2 + 0) ^ xlo) * 16));
    const unsigned bB = (unsigned)(m32 * 256 + (((hi * 2 + 1) ^ xlo) * 16));
    unsigned kterm[4];
    #pragma unroll
    for (int kc = 0; kc < 4; ++kc)
        kterm[kc] = (unsigned)(kc * 64) ^ xh16;

    // ---- staging offsets: wave stages 16 rows (4 KB) per tile, 4 async16 ----
    // chunk j covers rows wv*16 + j*4 + (lane>>4); dest granule = lane&15;
    // source supplies logical granule (lane&15) ^ (row&15).
    unsigned soff[4];
    #pragma unroll
    for (int j = 0; j < 4; ++j) {
        const int r = wv * 16 + j * 4 + (lane >> 4);
        const int gp = lane & 15;
        soff[j] = (unsigned)(r * 256 + ((gp ^ (r & 15)) * 16));
    }

    const unsigned char* Bglob = Pn + (size_t)(oct * 1024) * DDIM;

#define STG(T, BUF)                                                          \
    do {                                                                     \
        _Pragma("unroll")                                                    \
        for (int j = 0; j < 4; ++j)                                          \
            async16(Bglob + (size_t)(T) * 32768 + soff[j],                   \
                    lds + (BUF) * 32768 + wv * 4096 + j * 1024);             \
    } while (0)

    float rowpart[16];
    #pragma unroll
    for (int g = 0; g < 16; ++g) rowpart[g] = 0.0f;

    // ---- Prologue: stage tiles 0..2, full drain (also covers A-loads) ----
    STG(0, 0); STG(1, 1); STG(2, 2);
    asm volatile("s_waitcnt vmcnt(0)" ::: "memory");
    __builtin_amdgcn_s_barrier();

    // ---- Main loop: 8 col-slots of 128 fp8 cols ----
    // slot top: outstanding = tiles {i,i+1,i+2} = 12 loads; vmcnt(8)
    // drains tile i. Slots 6/7: 4/0 remain.
    for (int i = 0; i < 8; ++i) {
        if (i > 0) {
            if (i <= 5)       asm volatile("s_waitcnt vmcnt(8)" ::: "memory");
            else if (i == 6)  asm volatile("s_waitcnt vmcnt(4)" ::: "memory");
            else              asm volatile("s_waitcnt vmcnt(0)" ::: "memory");
            __builtin_amdgcn_s_barrier();   // frees buf (i+3)&3
        }
        if (i + 3 < 8) STG(i + 3, (i + 3) & 3);

        const unsigned char* Bp = lds + (i & 3) * 32768;
        f32x16 acc[4];
        #pragma unroll
        for (int n = 0; n < 4; ++n)
            #pragma unroll
            for (int g = 0; g < 16; ++g) acc[n][g] = 0.0f;

        #pragma unroll
        for (int kc = 0; kc < 4; ++kc) {
            A8 b[4];
            #pragma unroll
            for (int n = 0; n < 4; ++n) {
                b[n].h[0] = *(const int4v*)(Bp + bA + kterm[kc] + n * 8192);
                b[n].h[1] = *(const int4v*)(Bp + bB + kterm[kc] + n * 8192);
            }
            __builtin_amdgcn_s_setprio(1);
            #pragma unroll
            for (int n = 0; n < 4; ++n)
                acc[n] = __builtin_amdgcn_mfma_scale_f32_32x32x64_f8f6f4(
                    afr[kc].v, b[n].v, acc[n], 0, 0,
                    0, 0x7F7F7F7F, 0, 0x7F7F7F7F);   // fp8/fp8, unit scales
            __builtin_amdgcn_s_setprio(0);
        }

        // exp(5*sim) = 2^(sim*5*log2 e); all 4 col-blocks feed the same rows
        #pragma unroll
        for (int n = 0; n < 4; ++n)
            #pragma unroll
            for (int g = 0; g < 16; ++g)
                rowpart[g] += fexp2(acc[n][g] * 7.2134752044448169f);
    }
#undef STG

    // ---- Epilogue: reduce 32 column-lanes, one atomic per row-slot ----
    // C/D: col = lane&31, row = (g&3) + 8*(g>>2) + 4*hi.
    #pragma unroll
    for (int g = 0; g < 16; ++g) {
        float s = rowpart[g];
        s += __shfl_xor(s, 1);
        s += __shfl_xor(s, 2);
        s += __shfl_xor(s, 4);
        s += __shfl_xor(s, 8);
        s += __shfl_xor(s, 16);
        if (m32 == 0) {
            const int grow = stripe * 256 + wv * 32
                           + (g & 3) + 8 * (g >> 2) + 4 * hi;
            atomicAdd(&rowsum[grow], s);
        }
    }

    // ---- Fused finalize: last block computes the loss ----
    __threadfence();
    __syncthreads();   // this block's atomics are visible
    if (tid == 0)
        ticket_s = __hip_atomic_fetch_add(counter, 1, __ATOMIC_ACQ_REL,
                                          __HIP_MEMORY_SCOPE_AGENT);
    __syncthreads();
    if (ticket_s == 255) {
        float part = 0.0f;
        for (int i = tid; i < NROWS; i += 512) {
            const float rs = __hip_atomic_load(&rowsum[i], __ATOMIC_RELAXED,
                                               __HIP_MEMORY_SCOPE_AGENT);
            part += __logf(rs) - 5.0f * possim[i];
        }
        #pragma unroll
        for (int d = 1; d < 64; d <<= 1) part += __shfl_xor(part, d);
        if ((tid & 63) == 0) ws8[wv] = part;
        __syncthreads();
        if (tid == 0) {
            float tot = 0.0f;
            #pragma unroll
            for (int w = 0; w < 8; ++w) tot += ws8[w];
            out[0] = tot * (1.0f / (float)NROWS);
        }
    }
}

extern "C" void kernel_launch(void* const* d_in, const int* in_sizes, int n_in,
                              void* d_out, int out_size, void* d_ws, size_t ws_size,
                              hipStream_t stream) {
    const float* U = (const float*)d_in[0];
    const float* P = (const float*)d_in[1];
    float* out = (float*)d_out;
    char* ws = (char*)d_ws;
    // ws: Un fp8 (2 MB) | Pn fp8 (2 MB) | ... | rowsum f32 @8 MB | possim | counter
    unsigned char* Un = (unsigned char*)ws;
    unsigned char* Pn = (unsigned char*)(ws + 2097152);
    float* rowsum = (float*)(ws + 8388608);
    float* possim = (float*)(ws + 8388608 + 32768);
    int* counter  = (int*)(ws + 8388608 + 65536);

    normalize_kernel<<<NROWS / 4, 256, 0, stream>>>(U, P, Un, Pn, possim, rowsum,
                                                    out, counter);
    sim_exp_rowsum<<<256, 512, 0, stream>>>(Un, Pn, rowsum, possim, counter, out);
}